// Round 5
// baseline (451.809 us; speedup 1.0000x reference)
//
#include <hip/hip_runtime.h>
#include <math.h>

#define B_ 128
#define NTOK 577
#define P_ 576
#define D_ 768
#define G_ 17
#define KOCC 10
#define INV_TEMP 10.0f
#define U17 (1.0f / 17.0f)
#define NCHUNK 9

// ws layout (float offsets):
#define OFF_WT 0                                // [17][768] transposed weights
#define OFF_SIM (G_ * D_)                       // [B][576]
#define OFF_CLSINV (OFF_SIM + B_ * P_)          // [B]
#define OFF_GFP (OFF_CLSINV + B_)               // [NCHUNK][B][17][768]
#define GFP_PART ((size_t)B_ * G_ * D_)

// K0: blocks 0..127: feats[b][0]=cls, clsinv[b]; optional zero of group rows
//     (only needed for the atomic fallback path). blocks 128..144: gw -> wt.
__global__ __launch_bounds__(256) void k0_cls(const float* __restrict__ x,
                                              const float* __restrict__ gw,
                                              float* __restrict__ feats,
                                              float* __restrict__ clsinv,
                                              float* __restrict__ wt,
                                              int zero_groups) {
    if (blockIdx.x >= B_) {
        int g = blockIdx.x - B_;
        for (int d = threadIdx.x; d < D_; d += 256)
            wt[g * D_ + d] = gw[d * G_ + g];
        return;
    }
    int b = blockIdx.x;
    const float* cls = x + (size_t)b * NTOK * D_;
    float* fb = feats + (size_t)b * 18 * D_;
    float ss = 0.f;
    for (int i = threadIdx.x; i < D_ / 4; i += 256) {
        float4 v = ((const float4*)cls)[i];
        ((float4*)fb)[i] = v;
        ss = fmaf(v.x, v.x, fmaf(v.y, v.y, fmaf(v.z, v.z, fmaf(v.w, v.w, ss))));
    }
    if (zero_groups) {
        float4 z = {0.f, 0.f, 0.f, 0.f};
        for (int i = threadIdx.x; i < G_ * D_ / 4; i += 256)
            ((float4*)(fb + D_))[i] = z;
    }
    #pragma unroll
    for (int off = 32; off; off >>= 1) ss += __shfl_xor(ss, off, 64);
    __shared__ float red[4];
    int wave = threadIdx.x >> 6, lane = threadIdx.x & 63;
    if (lane == 0) red[wave] = ss;
    __syncthreads();
    if (threadIdx.x == 0) {
        float t = red[0] + red[1] + red[2] + red[3];
        clsinv[b] = 1.0f / fmaxf(sqrtf(t), 1e-12f);
    }
}

// K1 v5: scores + softmax ONLY. grid (NCHUNK, B_), block 512 (8 waves).
// Per-wave state halved vs r2: each wave owns 8 p-rows, each thread 2 rows
// (lr = lane&15 -> d-slice, rh = lane>>4). Accumulators 19x2 = 38 VGPR
// (vs 76) -> compiler can keep the 17 per-iteration w-loads in ONE deep
// vmcnt batch, and 8 waves/block give ~2x the co-resident work per SIMD
// to hide each L2 wait (r1/r2/r4 all pinned at 20-24% VALUBusy by
// per-wave latency exposure regardless of memory-path choice).
// w stays direct-from-L2 (r2: w-path not the bottleneck). LDS = 5KB only.
__global__ __launch_bounds__(512) void k1_score(const float* __restrict__ x,
                                                const float* __restrict__ wt,
                                                const float* __restrict__ clsinv,
                                                float* __restrict__ sim,
                                                float* __restrict__ attn) {
    __shared__ __align__(16) float atile[19 * 68];
    int tid = threadIdx.x;
    int b = blockIdx.y, chunk = blockIdx.x;
    const float* clsrow = x + (size_t)b * NTOK * D_;

    int lane = tid & 63, wave = tid >> 6;
    int lr = lane & 15, rh = lane >> 4;
    int lr4 = lr * 4;
    int pbase = wave * 8 + rh * 2;                 // 2 rows per thread
    const float* xp0 = x + ((size_t)(b * NTOK + 1 + chunk * 64 + pbase)) * D_ + lr4;
    const float* cp  = clsrow + lr4;

    float4 xv[2], xn[2], cv, cn;
    xv[0] = *(const float4*)(xp0);
    xv[1] = *(const float4*)(xp0 + D_);
    cv = *(const float4*)(cp);
    xn[0] = xv[0]; xn[1] = xv[1]; cn = cv;

    float s[19][2];
    #pragma unroll
    for (int i = 0; i < 19; ++i) { s[i][0] = 0.f; s[i][1] = 0.f; }

    for (int kc = 0; kc < 12; ++kc) {
        if (kc < 11) {
            xn[0] = *(const float4*)(xp0 + (kc + 1) * 64);
            xn[1] = *(const float4*)(xp0 + (kc + 1) * 64 + D_);
            cn = *(const float4*)(cp + (kc + 1) * 64);
        }
        const float* wk = wt + kc * 64 + lr4;
        #pragma unroll
        for (int g = 0; g < 17; ++g) {
            float4 w4 = *(const float4*)(wk + (size_t)g * D_);
            #pragma unroll
            for (int m = 0; m < 2; ++m)
                s[g][m] = fmaf(xv[m].x, w4.x, fmaf(xv[m].y, w4.y,
                          fmaf(xv[m].z, w4.z, fmaf(xv[m].w, w4.w, s[g][m]))));
        }
        #pragma unroll
        for (int m = 0; m < 2; ++m)
            s[17][m] = fmaf(xv[m].x, cv.x, fmaf(xv[m].y, cv.y,
                       fmaf(xv[m].z, cv.z, fmaf(xv[m].w, cv.w, s[17][m]))));
        #pragma unroll
        for (int m = 0; m < 2; ++m)
            s[18][m] = fmaf(xv[m].x, xv[m].x, fmaf(xv[m].y, xv[m].y,
                       fmaf(xv[m].z, xv[m].z, fmaf(xv[m].w, xv[m].w, s[18][m]))));
        xv[0] = xn[0]; xv[1] = xn[1]; cv = cn;
    }

    // reduce over the 16 d-slices within each row-group
    #pragma unroll
    for (int off = 8; off >= 1; off >>= 1)
        #pragma unroll
        for (int i = 0; i < 19; ++i)
            #pragma unroll
            for (int m = 0; m < 2; ++m)
                s[i][m] += __shfl_xor(s[i][m], off, 16);

    #pragma unroll
    for (int g = 0; g < 19; ++g) {
        if (lr == ((g < 16) ? g : 15)) {
            float2 v = {s[g][0], s[g][1]};
            *(float2*)&atile[g * 68 + pbase] = v;
        }
    }
    __syncthreads();

    if (tid < 64) {
        int p = chunk * 64 + tid;
        float v[17];
        float mx = -3.0e38f;
        #pragma unroll
        for (int g = 0; g < 17; ++g) {
            v[g] = atile[g * 68 + tid];
            mx = fmaxf(mx, v[g]);
        }
        float tot = 0.f;
        #pragma unroll
        for (int g = 0; g < 17; ++g) {
            v[g] = __expf((v[g] - mx) * INV_TEMP);
            tot += v[g];
        }
        float inv = 1.0f / tot;
        float* ap = attn + ((size_t)b * G_) * P_ + p;
        #pragma unroll
        for (int g = 0; g < 17; ++g) ap[(size_t)g * P_] = v[g] * inv;  // pre-occlusion
        float cd = atile[17 * 68 + tid];
        float sq = atile[18 * 68 + tid];
        sim[(size_t)b * P_ + p] = cd * clsinv[b] / fmaxf(sqrtf(sq), 1e-12f);
    }
}

// K3 v5: PV with pre-occlusion attn, separate kernel (separate rocprof row).
// grid (NCHUNK, B_), block 192. attn tile re-read from L2 (5MB total, hot);
// x chunk re-read from L2/L3 (streamed moments ago by k1). One gfp slab per
// chunk, plain stores (atomic-into-feats fallback if ws too small).
__global__ __launch_bounds__(192) void k3_pv(const float* __restrict__ x,
                                             const float* __restrict__ attn,
                                             float* __restrict__ gfp,
                                             float* __restrict__ feats,
                                             int use_part) {
    __shared__ __align__(16) float am[17 * 68];
    int tid = threadIdx.x;
    int chunk = blockIdx.x, b = blockIdx.y;

    for (int i = tid; i < 17 * 64; i += 192) {
        int g = i >> 6, p = i & 63;
        am[g * 68 + p] = attn[((size_t)b * G_ + g) * P_ + chunk * 64 + p];
    }
    __syncthreads();

    const float* xb = x + ((size_t)(b * NTOK) + 1 + chunk * 64) * D_ + tid * 4;
    float4 acc[G_];
    #pragma unroll
    for (int g = 0; g < G_; ++g) acc[g] = make_float4(0.f, 0.f, 0.f, 0.f);

    float4 c0 = *(const float4*)(xb + (size_t)0 * D_);
    float4 c1 = *(const float4*)(xb + (size_t)1 * D_);
    float4 c2 = *(const float4*)(xb + (size_t)2 * D_);
    float4 c3 = *(const float4*)(xb + (size_t)3 * D_);

    for (int pp = 0; pp < 64; pp += 4) {
        float4 n0 = c0, n1 = c1, n2 = c2, n3 = c3;
        if (pp + 4 < 64) {
            n0 = *(const float4*)(xb + (size_t)(pp + 4) * D_);
            n1 = *(const float4*)(xb + (size_t)(pp + 5) * D_);
            n2 = *(const float4*)(xb + (size_t)(pp + 6) * D_);
            n3 = *(const float4*)(xb + (size_t)(pp + 7) * D_);
        }
        #pragma unroll
        for (int g = 0; g < G_; ++g) {
            float4 a = *(const float4*)&am[g * 68 + pp];   // wave-uniform broadcast
            acc[g].x = fmaf(a.x, c0.x, fmaf(a.y, c1.x, fmaf(a.z, c2.x, fmaf(a.w, c3.x, acc[g].x))));
            acc[g].y = fmaf(a.x, c0.y, fmaf(a.y, c1.y, fmaf(a.z, c2.y, fmaf(a.w, c3.y, acc[g].y))));
            acc[g].z = fmaf(a.x, c0.z, fmaf(a.y, c1.z, fmaf(a.z, c2.z, fmaf(a.w, c3.z, acc[g].z))));
            acc[g].w = fmaf(a.x, c0.w, fmaf(a.y, c1.w, fmaf(a.z, c2.w, fmaf(a.w, c3.w, acc[g].w))));
        }
        c0 = n0; c1 = n1; c2 = n2; c3 = n3;
    }

    if (use_part) {
        float* gb = gfp + ((size_t)(chunk * B_ + b) * G_) * D_ + tid * 4;
        #pragma unroll
        for (int g = 0; g < G_; ++g) *(float4*)(gb + (size_t)g * D_) = acc[g];
    } else {
        float* fb = feats + ((size_t)(b * 18) + 1) * D_ + tid * 4;
        #pragma unroll
        for (int g = 0; g < G_; ++g) {
            atomicAdd(fb + (size_t)g * D_ + 0, acc[g].x);
            atomicAdd(fb + (size_t)g * D_ + 1, acc[g].y);
            atomicAdd(fb + (size_t)g * D_ + 2, acc[g].z);
            atomicAdd(fb + (size_t)g * D_ + 3, acc[g].w);
        }
    }
}

// K24: grid (B_), block 192. Wave 0: top-k (10 smallest sims, ties -> lower
// index). Meanwhile all threads sum the 9 gfp partial slabs (independent of
// top-k). Then: snapshot pre-occlusion attn at occluded columns, stamp 1/17,
// and subtract the per-g occluded contribution sum_t a0[g,t]*x[p_t].
__global__ __launch_bounds__(192) void k24_fin(const float* __restrict__ x,
                                               const float* __restrict__ sim,
                                               const float* __restrict__ gfp,
                                               float* __restrict__ attn,
                                               float* __restrict__ feats,
                                               int use_part) {
    __shared__ int s_occ[KOCC];
    __shared__ float s_a0[KOCC][G_];
    int b = blockIdx.x, tid = threadIdx.x;

    if (tid < 64) {
        int lane = tid;
        int base = lane * 9;
        float v[9];
        #pragma unroll
        for (int j = 0; j < 9; ++j) v[j] = sim[(size_t)b * P_ + base + j];
        for (int t = 0; t < KOCC; ++t) {
            float mv = 3.0e38f;
            int mi = 1 << 30;
            #pragma unroll
            for (int j = 0; j < 9; ++j) {
                if (v[j] < mv) { mv = v[j]; mi = base + j; }
            }
            #pragma unroll
            for (int off = 1; off < 64; off <<= 1) {
                float ov = __shfl_xor(mv, off, 64);
                int oi = __shfl_xor(mi, off, 64);
                if (ov < mv || (ov == mv && oi < mi)) { mv = ov; mi = oi; }
            }
            if (lane == 0) s_occ[t] = mi;
            int loc = mi - base;
            if (loc >= 0 && loc < 9) v[loc] = 3.0e38f;
        }
    }

    // Partial sums: independent of top-k, so waves 1-2 start immediately.
    float4 acc[G_];
    float* fb = feats + ((size_t)(b * 18) + 1) * D_ + tid * 4;
    if (use_part) {
        #pragma unroll
        for (int g = 0; g < G_; ++g) acc[g] = make_float4(0.f, 0.f, 0.f, 0.f);
        for (int pc = 0; pc < NCHUNK; ++pc) {
            const float* gb = gfp + ((size_t)(pc * B_ + b) * G_) * D_ + tid * 4;
            #pragma unroll
            for (int g = 0; g < G_; ++g) {
                float4 v = *(const float4*)(gb + (size_t)g * D_);
                acc[g].x += v.x; acc[g].y += v.y; acc[g].z += v.z; acc[g].w += v.w;
            }
        }
    } else {
        #pragma unroll
        for (int g = 0; g < G_; ++g) acc[g] = *(const float4*)(fb + (size_t)g * D_);
    }
    __syncthreads();   // s_occ ready

    // Snapshot pre-occlusion attn at occluded columns, then stamp 1/17.
    // Each (t,g) entry is read and overwritten by the SAME thread -> no race.
    for (int i = tid; i < KOCC * G_; i += 192) {
        int t = i / G_, g = i - t * G_;
        size_t idx = ((size_t)b * G_ + g) * P_ + s_occ[t];
        s_a0[t][g] = attn[idx];
        attn[idx] = U17;
    }
    __syncthreads();   // s_a0 ready

    #pragma unroll
    for (int t = 0; t < KOCC; ++t) {
        float4 xo = *(const float4*)(x + ((size_t)(b * NTOK) + 1 + s_occ[t]) * D_ + tid * 4);
        #pragma unroll
        for (int g = 0; g < G_; ++g) {
            float a0 = s_a0[t][g];
            acc[g].x = fmaf(-a0, xo.x, acc[g].x);
            acc[g].y = fmaf(-a0, xo.y, acc[g].y);
            acc[g].z = fmaf(-a0, xo.z, acc[g].z);
            acc[g].w = fmaf(-a0, xo.w, acc[g].w);
        }
    }
    #pragma unroll
    for (int g = 0; g < G_; ++g) *(float4*)(fb + (size_t)g * D_) = acc[g];
}

extern "C" void kernel_launch(void* const* d_in, const int* in_sizes, int n_in,
                              void* d_out, int out_size, void* d_ws, size_t ws_size,
                              hipStream_t stream) {
    const float* x  = (const float*)d_in[0];
    const float* gw = (const float*)d_in[1];
    float* feats = (float*)d_out;                               // B*18*D
    float* attn  = (float*)d_out + (size_t)B_ * 18 * D_;        // B*17*P
    float* wt      = (float*)d_ws + OFF_WT;
    float* sim     = (float*)d_ws + OFF_SIM;
    float* clsinv  = (float*)d_ws + OFF_CLSINV;
    float* gfp     = (float*)d_ws + OFF_GFP;

    int use_part = (((size_t)OFF_GFP + (size_t)NCHUNK * GFP_PART) * sizeof(float) <= ws_size);

    k0_cls<<<B_ + G_, 256, 0, stream>>>(x, gw, feats, clsinv, wt, !use_part);
    k1_score<<<dim3(NCHUNK, B_), 512, 0, stream>>>(x, wt, clsinv, sim, attn);
    k3_pv<<<dim3(NCHUNK, B_), 192, 0, stream>>>(x, attn, gfp, feats, use_part);
    k24_fin<<<B_, 192, 0, stream>>>(x, sim, gfp, attn, feats, use_part);
}

// Round 6
// 381.433 us; speedup vs baseline: 1.1845x; 1.1845x over previous
//
#include <hip/hip_runtime.h>
#include <math.h>

#define B_ 128
#define NTOK 577
#define P_ 576
#define D_ 768
#define G_ 17
#define KOCC 10
#define INV_TEMP 10.0f
#define U17 (1.0f / 17.0f)
#define NCHUNK 9

// ws layout (float offsets):
#define OFF_WT 0                                // [17][768] transposed weights
#define OFF_SIM (G_ * D_)                       // [B][576]
#define OFF_CLSINV (OFF_SIM + B_ * P_)          // [B]
#define OFF_GFP (OFF_CLSINV + B_)               // [NCHUNK][B][17][768]
#define GFP_PART ((size_t)B_ * G_ * D_)

// K0: blocks 0..127: feats[b][0]=cls, clsinv[b]; optional zero of group rows
//     (only needed for the atomic fallback path). blocks 128..144: gw -> wt.
__global__ __launch_bounds__(256) void k0_cls(const float* __restrict__ x,
                                              const float* __restrict__ gw,
                                              float* __restrict__ feats,
                                              float* __restrict__ clsinv,
                                              float* __restrict__ wt,
                                              int zero_groups) {
    if (blockIdx.x >= B_) {
        int g = blockIdx.x - B_;
        for (int d = threadIdx.x; d < D_; d += 256)
            wt[g * D_ + d] = gw[d * G_ + g];
        return;
    }
    int b = blockIdx.x;
    const float* cls = x + (size_t)b * NTOK * D_;
    float* fb = feats + (size_t)b * 18 * D_;
    float ss = 0.f;
    for (int i = threadIdx.x; i < D_ / 4; i += 256) {
        float4 v = ((const float4*)cls)[i];
        ((float4*)fb)[i] = v;
        ss = fmaf(v.x, v.x, fmaf(v.y, v.y, fmaf(v.z, v.z, fmaf(v.w, v.w, ss))));
    }
    if (zero_groups) {
        float4 z = {0.f, 0.f, 0.f, 0.f};
        for (int i = threadIdx.x; i < G_ * D_ / 4; i += 256)
            ((float4*)(fb + D_))[i] = z;
    }
    #pragma unroll
    for (int off = 32; off; off >>= 1) ss += __shfl_xor(ss, off, 64);
    __shared__ float red[4];
    int wave = threadIdx.x >> 6, lane = threadIdx.x & 63;
    if (lane == 0) red[wave] = ss;
    __syncthreads();
    if (threadIdx.x == 0) {
        float t = red[0] + red[1] + red[2] + red[3];
        clsinv[b] = 1.0f / fmaxf(sqrtf(t), 1e-12f);
    }
}

// K13 v6: fused scores + softmax + PV. grid (NCHUNK, B_), block 512 (8 waves).
// KEY CHANGE vs r1/r2/r5: w (51KB) + cls (3KB) staged into LDS ONCE per
// block. Audit of r5 counters showed per-wave redundant w re-fetches were
// ~480MB of ~735MB through the per-CU L1-miss path (2x the compulsory x
// traffic) -- every variant so far re-loaded w from L2 every kc iteration
// and stalled ~5300 cyc/iter on it. Now the K-loop's only global traffic
// is the prefetched x stream; w/cls come from conflict-free ds_read_b128
// (lr-contiguous 256B, 2-way bank aliasing = free).
// r3's poison avoided: no launch_bounds VGPR cap, no 3x unroll; 2-row
// threads keep accumulators at 38 VGPR (no spills).
// LDS 59KB -> 2 blocks/CU (16 waves/CU, matches the VGPR-68..90 limit).
__global__ __launch_bounds__(512) void k13_score_pv(const float* __restrict__ x,
                                                    const float* __restrict__ wt,
                                                    const float* __restrict__ clsinv,
                                                    float* __restrict__ sim,
                                                    float* __restrict__ attn,
                                                    float* __restrict__ gfp,
                                                    float* __restrict__ feats,
                                                    int use_part) {
    __shared__ __align__(16) float wlds[G_ * D_];   // 52224 B
    __shared__ __align__(16) float clds[D_];        // 3072 B
    __shared__ __align__(16) float atile[19 * 68];  // 5168 B

    int tid = threadIdx.x;
    int b = blockIdx.y, chunk = blockIdx.x;
    const float* clsrow = x + (size_t)b * NTOK * D_;

    int lane = tid & 63, wave = tid >> 6;
    int lr = lane & 15, rh = lane >> 4;
    int lr4 = lr * 4;
    int pbase = wave * 8 + rh * 2;                  // 2 p-rows per thread
    const float* xp0 = x + ((size_t)(b * NTOK + 1 + chunk * 64 + pbase)) * D_ + lr4;

    // issue first x prefetch before staging (independent of LDS)
    float4 xv[2], xn[2];
    xv[0] = *(const float4*)(xp0);
    xv[1] = *(const float4*)(xp0 + D_);

    // stage w + cls -> LDS once
    for (int i = tid; i < G_ * D_ / 4; i += 512)
        ((float4*)wlds)[i] = ((const float4*)wt)[i];
    for (int i = tid; i < D_ / 4; i += 512)
        ((float4*)clds)[i] = ((const float4*)clsrow)[i];

    float s[19][2];
    #pragma unroll
    for (int i = 0; i < 19; ++i) { s[i][0] = 0.f; s[i][1] = 0.f; }

    xn[0] = xv[0]; xn[1] = xv[1];
    __syncthreads();   // wlds/clds ready

    for (int kc = 0; kc < 12; ++kc) {
        if (kc < 11) {
            xn[0] = *(const float4*)(xp0 + (kc + 1) * 64);
            xn[1] = *(const float4*)(xp0 + (kc + 1) * 64 + D_);
        }
        float4 cls4 = *(const float4*)&clds[kc * 64 + lr4];
        const float* wk = wlds + kc * 64 + lr4;
        #pragma unroll
        for (int g = 0; g < 17; ++g) {
            float4 w4 = *(const float4*)(wk + (size_t)g * D_);
            #pragma unroll
            for (int m = 0; m < 2; ++m)
                s[g][m] = fmaf(xv[m].x, w4.x, fmaf(xv[m].y, w4.y,
                          fmaf(xv[m].z, w4.z, fmaf(xv[m].w, w4.w, s[g][m]))));
        }
        #pragma unroll
        for (int m = 0; m < 2; ++m)
            s[17][m] = fmaf(xv[m].x, cls4.x, fmaf(xv[m].y, cls4.y,
                       fmaf(xv[m].z, cls4.z, fmaf(xv[m].w, cls4.w, s[17][m]))));
        #pragma unroll
        for (int m = 0; m < 2; ++m)
            s[18][m] = fmaf(xv[m].x, xv[m].x, fmaf(xv[m].y, xv[m].y,
                       fmaf(xv[m].z, xv[m].z, fmaf(xv[m].w, xv[m].w, s[18][m]))));
        xv[0] = xn[0]; xv[1] = xn[1];
    }

    // reduce over the 16 d-slices within each row-group
    #pragma unroll
    for (int off = 8; off >= 1; off >>= 1)
        #pragma unroll
        for (int i = 0; i < 19; ++i)
            #pragma unroll
            for (int m = 0; m < 2; ++m)
                s[i][m] += __shfl_xor(s[i][m], off, 16);

    #pragma unroll
    for (int g = 0; g < 19; ++g) {
        if (lr == ((g < 16) ? g : 15)) {
            float2 v = {s[g][0], s[g][1]};
            *(float2*)&atile[g * 68 + pbase] = v;
        }
    }
    __syncthreads();

    if (tid < 64) {
        int p = chunk * 64 + tid;
        float v[17];
        float mx = -3.0e38f;
        #pragma unroll
        for (int g = 0; g < 17; ++g) {
            v[g] = atile[g * 68 + tid];
            mx = fmaxf(mx, v[g]);
        }
        float tot = 0.f;
        #pragma unroll
        for (int g = 0; g < 17; ++g) {
            v[g] = __expf((v[g] - mx) * INV_TEMP);
            tot += v[g];
        }
        float inv = 1.0f / tot;
        float* ap = attn + ((size_t)b * G_) * P_ + p;
        #pragma unroll
        for (int g = 0; g < 17; ++g) {
            float av = v[g] * inv;
            ap[(size_t)g * P_] = av;        // pre-occlusion attn to global
            atile[g * 68 + tid] = av;       // normalized copy for PV phase
        }
        float cd = atile[17 * 68 + tid];
        float sq = atile[18 * 68 + tid];
        sim[(size_t)b * P_ + p] = cd * clsinv[b] / fmaxf(sqrtf(sq), 1e-12f);
    }
    __syncthreads();

    if (tid >= 192) return;
    // PV phase: re-read this block's own x chunk from global (L2/L3-hot).
    const float* xb = x + ((size_t)(b * NTOK) + 1 + chunk * 64) * D_ + tid * 4;
    float4 acc[G_];
    #pragma unroll
    for (int g = 0; g < G_; ++g) acc[g] = make_float4(0.f, 0.f, 0.f, 0.f);

    float4 c0 = *(const float4*)(xb + (size_t)0 * D_);
    float4 c1 = *(const float4*)(xb + (size_t)1 * D_);
    float4 c2 = *(const float4*)(xb + (size_t)2 * D_);
    float4 c3 = *(const float4*)(xb + (size_t)3 * D_);

    for (int pp = 0; pp < 64; pp += 4) {
        float4 n0 = c0, n1 = c1, n2 = c2, n3 = c3;
        if (pp + 4 < 64) {
            n0 = *(const float4*)(xb + (size_t)(pp + 4) * D_);
            n1 = *(const float4*)(xb + (size_t)(pp + 5) * D_);
            n2 = *(const float4*)(xb + (size_t)(pp + 6) * D_);
            n3 = *(const float4*)(xb + (size_t)(pp + 7) * D_);
        }
        #pragma unroll
        for (int g = 0; g < G_; ++g) {
            float4 a = *(const float4*)&atile[g * 68 + pp];   // wave-uniform broadcast
            acc[g].x = fmaf(a.x, c0.x, fmaf(a.y, c1.x, fmaf(a.z, c2.x, fmaf(a.w, c3.x, acc[g].x))));
            acc[g].y = fmaf(a.x, c0.y, fmaf(a.y, c1.y, fmaf(a.z, c2.y, fmaf(a.w, c3.y, acc[g].y))));
            acc[g].z = fmaf(a.x, c0.z, fmaf(a.y, c1.z, fmaf(a.z, c2.z, fmaf(a.w, c3.z, acc[g].z))));
            acc[g].w = fmaf(a.x, c0.w, fmaf(a.y, c1.w, fmaf(a.z, c2.w, fmaf(a.w, c3.w, acc[g].w))));
        }
        c0 = n0; c1 = n1; c2 = n2; c3 = n3;
    }

    if (use_part) {
        float* gb = gfp + ((size_t)(chunk * B_ + b) * G_) * D_ + tid * 4;
        #pragma unroll
        for (int g = 0; g < G_; ++g) *(float4*)(gb + (size_t)g * D_) = acc[g];
    } else {
        float* fb = feats + ((size_t)(b * 18) + 1) * D_ + tid * 4;
        #pragma unroll
        for (int g = 0; g < G_; ++g) {
            atomicAdd(fb + (size_t)g * D_ + 0, acc[g].x);
            atomicAdd(fb + (size_t)g * D_ + 1, acc[g].y);
            atomicAdd(fb + (size_t)g * D_ + 2, acc[g].z);
            atomicAdd(fb + (size_t)g * D_ + 3, acc[g].w);
        }
    }
}

// K24: grid (B_), block 192. Wave 0: top-k (10 smallest sims, ties -> lower
// index). Meanwhile all threads sum the 9 gfp partial slabs (independent of
// top-k). Then: snapshot pre-occlusion attn at occluded columns, stamp 1/17,
// and subtract the per-g occluded contribution sum_t a0[g,t]*x[p_t].
__global__ __launch_bounds__(192) void k24_fin(const float* __restrict__ x,
                                               const float* __restrict__ sim,
                                               const float* __restrict__ gfp,
                                               float* __restrict__ attn,
                                               float* __restrict__ feats,
                                               int use_part) {
    __shared__ int s_occ[KOCC];
    __shared__ float s_a0[KOCC][G_];
    int b = blockIdx.x, tid = threadIdx.x;

    if (tid < 64) {
        int lane = tid;
        int base = lane * 9;
        float v[9];
        #pragma unroll
        for (int j = 0; j < 9; ++j) v[j] = sim[(size_t)b * P_ + base + j];
        for (int t = 0; t < KOCC; ++t) {
            float mv = 3.0e38f;
            int mi = 1 << 30;
            #pragma unroll
            for (int j = 0; j < 9; ++j) {
                if (v[j] < mv) { mv = v[j]; mi = base + j; }
            }
            #pragma unroll
            for (int off = 1; off < 64; off <<= 1) {
                float ov = __shfl_xor(mv, off, 64);
                int oi = __shfl_xor(mi, off, 64);
                if (ov < mv || (ov == mv && oi < mi)) { mv = ov; mi = oi; }
            }
            if (lane == 0) s_occ[t] = mi;
            int loc = mi - base;
            if (loc >= 0 && loc < 9) v[loc] = 3.0e38f;
        }
    }

    // Partial sums: independent of top-k, so waves 1-2 start immediately.
    float4 acc[G_];
    float* fb = feats + ((size_t)(b * 18) + 1) * D_ + tid * 4;
    if (use_part) {
        #pragma unroll
        for (int g = 0; g < G_; ++g) acc[g] = make_float4(0.f, 0.f, 0.f, 0.f);
        for (int pc = 0; pc < NCHUNK; ++pc) {
            const float* gb = gfp + ((size_t)(pc * B_ + b) * G_) * D_ + tid * 4;
            #pragma unroll
            for (int g = 0; g < G_; ++g) {
                float4 v = *(const float4*)(gb + (size_t)g * D_);
                acc[g].x += v.x; acc[g].y += v.y; acc[g].z += v.z; acc[g].w += v.w;
            }
        }
    } else {
        #pragma unroll
        for (int g = 0; g < G_; ++g) acc[g] = *(const float4*)(fb + (size_t)g * D_);
    }
    __syncthreads();   // s_occ ready

    // Snapshot pre-occlusion attn at occluded columns, then stamp 1/17.
    // Each (t,g) entry is read and overwritten by the SAME thread -> no race.
    for (int i = tid; i < KOCC * G_; i += 192) {
        int t = i / G_, g = i - t * G_;
        size_t idx = ((size_t)b * G_ + g) * P_ + s_occ[t];
        s_a0[t][g] = attn[idx];
        attn[idx] = U17;
    }
    __syncthreads();   // s_a0 ready

    #pragma unroll
    for (int t = 0; t < KOCC; ++t) {
        float4 xo = *(const float4*)(x + ((size_t)(b * NTOK) + 1 + s_occ[t]) * D_ + tid * 4);
        #pragma unroll
        for (int g = 0; g < G_; ++g) {
            float a0 = s_a0[t][g];
            acc[g].x = fmaf(-a0, xo.x, acc[g].x);
            acc[g].y = fmaf(-a0, xo.y, acc[g].y);
            acc[g].z = fmaf(-a0, xo.z, acc[g].z);
            acc[g].w = fmaf(-a0, xo.w, acc[g].w);
        }
    }
    #pragma unroll
    for (int g = 0; g < G_; ++g) *(float4*)(fb + (size_t)g * D_) = acc[g];
}

extern "C" void kernel_launch(void* const* d_in, const int* in_sizes, int n_in,
                              void* d_out, int out_size, void* d_ws, size_t ws_size,
                              hipStream_t stream) {
    const float* x  = (const float*)d_in[0];
    const float* gw = (const float*)d_in[1];
    float* feats = (float*)d_out;                               // B*18*D
    float* attn  = (float*)d_out + (size_t)B_ * 18 * D_;        // B*17*P
    float* wt      = (float*)d_ws + OFF_WT;
    float* sim     = (float*)d_ws + OFF_SIM;
    float* clsinv  = (float*)d_ws + OFF_CLSINV;
    float* gfp     = (float*)d_ws + OFF_GFP;

    int use_part = (((size_t)OFF_GFP + (size_t)NCHUNK * GFP_PART) * sizeof(float) <= ws_size);

    k0_cls<<<B_ + G_, 256, 0, stream>>>(x, gw, feats, clsinv, wt, !use_part);
    k13_score_pv<<<dim3(NCHUNK, B_), 512, 0, stream>>>(x, wt, clsinv, sim, attn, gfp, feats, use_part);
    k24_fin<<<B_, 192, 0, stream>>>(x, sim, gfp, attn, feats, use_part);
}